// Round 10
// baseline (196.423 us; speedup 1.0000x reference)
//
#include <hip/hip_runtime.h>
#include <hip/hip_bf16.h>
#include <math.h>

// ---------------------------------------------------------------------------
// GATv2 2-layer forward. N=50000, E=500000 (+N self loops), IN_F=128, H=4.
// Round 10: fp8 reverted (absmax 0.047 > 0.025). Both agg kernels now
// 4 edges/wave (16 lanes/edge): agg1 8 ch/lane, agg2 16 ch/lane, quad-DPP
// logit reduce, depth-3 row prefetch. GEMM/CSR from round 8.
// ---------------------------------------------------------------------------

typedef _Float16 half2v __attribute__((ext_vector_type(2)));
typedef _Float16 half4v __attribute__((ext_vector_type(4)));
typedef _Float16 half8v __attribute__((ext_vector_type(8)));
typedef float float4v __attribute__((ext_vector_type(4)));

template <int CTRL>
static __device__ __forceinline__ float dppadd(float x) {
  int y = __builtin_amdgcn_update_dpp(0, __float_as_int(x), CTRL, 0xf, 0xf, true);
  return x + __int_as_float(y);
}

// sum across each aligned 4-lane quad (all lanes get the quad total)
static __device__ __forceinline__ float red4dpp(float p) {
  p = dppadd<0xB1>(p);  // quad_perm xor1
  p = dppadd<0x4E>(p);  // quad_perm xor2
  return p;
}

// ---------------- fused conversions + degree count ----------------

__global__ void fused_cvt_count_kernel(
    const float* __restrict__ x,
    const float* __restrict__ wl1, const float* __restrict__ wr1,
    const float* __restrict__ wl2, const float* __restrict__ wr2,
    _Float16* __restrict__ xb, _Float16* __restrict__ wb,
    const int* __restrict__ dst, int* __restrict__ deg, int n4x, int E) {
  int i = blockIdx.x * blockDim.x + threadIdx.x;
  int stride = gridDim.x * blockDim.x;
  int total = n4x + 24576 + E;
  for (; i < total; i += stride) {
    if (i < n4x) {
      float4 v = ((const float4*)x)[i];
      half4v o = {(_Float16)v.x, (_Float16)v.y, (_Float16)v.z, (_Float16)v.w};
      ((half4v*)xb)[i] = o;
    } else if (i < n4x + 24576) {
      int fj = (i - n4x) * 4;
      const float* src;
      int so;
      if (fj < 16384) { src = wl1; so = fj; }
      else if (fj < 32768) { src = wr1; so = fj - 16384; }
      else if (fj < 65536) { src = wl2; so = fj - 32768; }
      else { src = wr2; so = fj - 65536; }
      float4 v = *(const float4*)(src + so);
      half4v o = {(_Float16)v.x, (_Float16)v.y, (_Float16)v.z, (_Float16)v.w};
      *(half4v*)(wb + fj) = o;
    } else {
      atomicAdd(&deg[dst[i - n4x - 24576]], 1);
    }
  }
}

// ---------------- CSR build ----------------

__global__ void partial_kernel(const int* __restrict__ deg, int* __restrict__ partial, int N) {
  int t = threadIdx.x;
  int i = blockIdx.x * 256 + t;
  int v = (i < N) ? deg[i] : 0;
  v += __shfl_xor(v, 1); v += __shfl_xor(v, 2); v += __shfl_xor(v, 4);
  v += __shfl_xor(v, 8); v += __shfl_xor(v, 16); v += __shfl_xor(v, 32);
  __shared__ int ws[4];
  if ((t & 63) == 0) ws[t >> 6] = v;
  __syncthreads();
  if (t == 0) partial[blockIdx.x] = ws[0] + ws[1] + ws[2] + ws[3];
}

__global__ void scan_final_kernel(const int* __restrict__ deg, const int* __restrict__ partial,
                                  int* __restrict__ row_ptr, int* __restrict__ cursor,
                                  int N, int E, int nb) {
  __shared__ int sp[256];
  __shared__ int s[256];
  int t = threadIdx.x;
  int pv = (t < nb) ? partial[t] : 0;
  sp[t] = pv;
  __syncthreads();
  for (int off = 1; off < 256; off <<= 1) {
    int u = (t >= off) ? sp[t - off] : 0;
    __syncthreads();
    sp[t] += u;
    __syncthreads();
  }
  int blockpre = (blockIdx.x > 0) ? sp[blockIdx.x - 1] : 0;
  int i = blockIdx.x * 256 + t;
  int v = (i < N) ? deg[i] : 0;
  s[t] = v;
  __syncthreads();
  for (int off = 1; off < 256; off <<= 1) {
    int u = (t >= off) ? s[t - off] : 0;
    __syncthreads();
    s[t] += u;
    __syncthreads();
  }
  int excl = s[t] - v + blockpre;
  if (i < N) {
    row_ptr[i] = excl;
    cursor[i] = excl;
  }
  if (blockIdx.x == 0 && t == 0) row_ptr[N] = E;
}

__global__ void fill_kernel(const int* __restrict__ src, const int* __restrict__ dst,
                            int* __restrict__ cursor, int* __restrict__ col, int E) {
  int i = blockIdx.x * blockDim.x + threadIdx.x;
  if (i < E) {
    int d = dst[i];
    int pos = atomicAdd(&cursor[d], 1);
    col[pos] = src[i];
  }
}

// ---------------- fp16 MFMA GEMM, LDS-staged W ----------------
__global__ __launch_bounds__(256) void gemm_mfma2(
    const _Float16* __restrict__ A, const _Float16* __restrict__ Wa,
    const _Float16* __restrict__ Wb, _Float16* __restrict__ Ca,
    _Float16* __restrict__ Cb, int N, int Oa, int ldC) {
  __shared__ _Float16 lds[32768];  // 64KB
  int t = threadIdx.x;
  int gbase = blockIdx.y * 256;
#pragma unroll
  for (int i = 0; i < 16; ++i) {
    int c = t + i * 256;
    int row = c >> 4, kc = c & 15;
    int grow = gbase + row;
    const _Float16* srcW =
        (grow < Oa) ? (Wa + (size_t)grow * 128) : (Wb + (size_t)(grow - Oa) * 128);
    half8v v = *(const half8v*)(srcW + kc * 8);
    int off16 = (row << 4) | (kc ^ (row & 7));
    *(half8v*)((char*)lds + (off16 << 4)) = v;
  }
  __syncthreads();
  int wv = t >> 6, lane = t & 63;
  int l15 = lane & 15, l4 = lane >> 4;
  int row0 = blockIdx.x * 64 + (wv & 1) * 32;
  int colw = (wv >> 1) * 128;
  int gc = gbase + colw;
  half8v xf[2][4];
#pragma unroll
  for (int rg = 0; rg < 2; ++rg) {
    int r = row0 + rg * 16 + l15;
    bool valid = r < N;
    const half8v* Ar = (const half8v*)(A + (size_t)r * 128 + l4 * 8);
#pragma unroll
    for (int kk = 0; kk < 4; ++kk) {
      half8v z = {};
      xf[rg][kk] = valid ? Ar[kk * 4] : z;
    }
  }
  int wrow = colw + l15;
  float4v acc[2][8] = {};
#pragma unroll
  for (int kk = 0; kk < 4; ++kk) {
    int xorterm = ((kk * 4 + l4) ^ (l15 & 7)) << 4;
    const char* base = (const char*)lds + wrow * 256 + xorterm;
    half8v wf[8];
#pragma unroll
    for (int ot = 0; ot < 8; ++ot) wf[ot] = *(const half8v*)(base + ot * 4096);
#pragma unroll
    for (int ot = 0; ot < 8; ++ot) {
      acc[0][ot] = __builtin_amdgcn_mfma_f32_16x16x32_f16(wf[ot], xf[0][kk], acc[0][ot], 0, 0, 0);
      acc[1][ot] = __builtin_amdgcn_mfma_f32_16x16x32_f16(wf[ot], xf[1][kk], acc[1][ot], 0, 0, 0);
    }
  }
  bool isA = gc < Oa;
  _Float16* C = isA ? Ca : Cb;
  int cb = isA ? gc : gc - Oa;
#pragma unroll
  for (int rg = 0; rg < 2; ++rg) {
    int r = row0 + rg * 16 + l15;
    if (r < N) {
#pragma unroll
      for (int ot = 0; ot < 8; ++ot) {
        half4v o = {(_Float16)acc[rg][ot][0], (_Float16)acc[rg][ot][1],
                    (_Float16)acc[rg][ot][2], (_Float16)acc[rg][ot][3]};
        *(half4v*)(C + (size_t)r * ldC + cb + ot * 16 + l4 * 4) = o;
      }
    }
  }
}

// ---------------- aggregation: 4 edges/wave ----------------
// No max-subtraction (logits O(6), softmax shift-invariant). att pre-scaled
// by log2(e) so w = exp2(p).

// Layer 1: D=128. eslot=lane>>4 (4 edges), sub=lane&15, 8 ch/lane (16B load).
// Head = 32 ch = 4 subs -> quad DPP reduce. f32 accumulation; f16 output h.
__global__ __launch_bounds__(128) void agg1_kernel(
    const _Float16* __restrict__ xl, const _Float16* __restrict__ xr,
    const float* __restrict__ att, const float* __restrict__ bias,
    const int* __restrict__ row_ptr, const int* __restrict__ col,
    _Float16* __restrict__ hout, int N) {
  int wid = (blockIdx.x * blockDim.x + threadIdx.x) >> 6;
  int lane = threadIdx.x & 63;
  if (wid >= N) return;
  int eslot = lane >> 4, sub = lane & 15;
  const uint d0 = (uint)sub * 8u;
  const float L2E = 1.44269504f;
  half8v xrv = *(const half8v*)(xr + (((uint)wid << 7) | d0));
  float4 af0 = *(const float4*)(att + d0);
  float4 af1 = *(const float4*)(att + d0 + 4);
  half2v at4[4] = {{(_Float16)(af0.x * L2E), (_Float16)(af0.y * L2E)},
                   {(_Float16)(af0.z * L2E), (_Float16)(af0.w * L2E)},
                   {(_Float16)(af1.x * L2E), (_Float16)(af1.y * L2E)},
                   {(_Float16)(af1.z * L2E), (_Float16)(af1.w * L2E)}};
  half8v k8 = {(_Float16)0.2f, (_Float16)0.2f, (_Float16)0.2f, (_Float16)0.2f,
               (_Float16)0.2f, (_Float16)0.2f, (_Float16)0.2f, (_Float16)0.2f};
  int e0 = row_ptr[wid];
  int deg = row_ptr[wid + 1] - e0;
  const int* ecol = col + e0;
  float s = 0.f, a[8] = {};
  auto edge = [&](half8v v, bool valid) {
    half8v u = v + xrv;
    half8v lr = __builtin_elementwise_max(u, u * k8);
    float pA = __builtin_amdgcn_fdot2((half2v){lr[0], lr[1]}, at4[0], 0.f, false);
    pA = __builtin_amdgcn_fdot2((half2v){lr[2], lr[3]}, at4[1], pA, false);
    float pB = __builtin_amdgcn_fdot2((half2v){lr[4], lr[5]}, at4[2], 0.f, false);
    pB = __builtin_amdgcn_fdot2((half2v){lr[6], lr[7]}, at4[3], pB, false);
    float p = red4dpp(pA + pB);  // head sum (4 subs)
    float w = valid ? exp2f(p) : 0.f;
    s += w;
#pragma unroll
    for (int k = 0; k < 8; ++k) a[k] = fmaf(w, (float)v[k], a[k]);
  };
  auto ld = [&](uint node) { return *(const half8v*)(xl + ((node << 7) | d0)); };
  edge(ld((uint)wid), eslot == 0);  // self loop (counted once)
  if (deg > 0) {
    int dm1 = deg - 1;
    half8v vA = ld((uint)ecol[min(eslot, dm1)]);
    half8v vB = ld((uint)ecol[min(eslot + 4, dm1)]);
    half8v vC = ld((uint)ecol[min(eslot + 8, dm1)]);
    int M = deg >> 2, pf = eslot + 12;
#pragma unroll 2
    for (int j = 0; j < M; ++j) {
      half8v vD = ld((uint)ecol[min(pf, dm1)]);  // prefetch d3
      edge(vA, true);
      vA = vB; vB = vC; vC = vD; pf += 4;
    }
    int T = deg & 3;
    if (T) edge(vA, eslot < T);
  }
  // combine 4 edge slots (lanes l, l^16, l^32, l^48)
  s += __shfl_xor(s, 16); s += __shfl_xor(s, 32);
#pragma unroll
  for (int k = 0; k < 8; ++k) {
    a[k] += __shfl_xor(a[k], 16);
    a[k] += __shfl_xor(a[k], 32);
  }
  float inv = 1.f / (s + 1e-16f);
  if (eslot == 0) {
    float4 b0 = *(const float4*)(bias + d0);
    float4 b1 = *(const float4*)(bias + d0 + 4);
    float bb[8] = {b0.x, b0.y, b0.z, b0.w, b1.x, b1.y, b1.z, b1.w};
    half8v o;
#pragma unroll
    for (int k = 0; k < 8; ++k) {
      float tv = a[k] * inv + bb[k];
      tv = tv > 0.f ? tv : __expf(tv) - 1.f;  // ELU
      o[k] = (_Float16)tv;
    }
    *(half8v*)(hout + (((uint)wid << 7) | d0)) = o;
  }
}

// Layer 2: D=256. eslot=lane>>4 (4 edges), sub=lane&15, 16 ch/lane (2x16B).
// Head = 64 ch = 4 subs -> quad DPP reduce. Head-mean via shfl_xor(4,8);
// lanes 0-3 write 16 f32 each.
__global__ __launch_bounds__(128) void agg2_kernel(
    const _Float16* __restrict__ xl, const _Float16* __restrict__ xr,
    const float* __restrict__ att, const float* __restrict__ bias,
    const int* __restrict__ row_ptr, const int* __restrict__ col,
    float* __restrict__ out, int N) {
  int wid = (blockIdx.x * blockDim.x + threadIdx.x) >> 6;
  int lane = threadIdx.x & 63;
  if (wid >= N) return;
  int eslot = lane >> 4, sub = lane & 15;
  const uint d0 = (uint)sub * 16u;
  const float L2E = 1.44269504f;
  const _Float16* xrp = xr + (((uint)wid << 8) | d0);
  half8v xra = *(const half8v*)xrp;
  half8v xrb = *(const half8v*)(xrp + 8);
  half2v at8[8];
#pragma unroll
  for (int k = 0; k < 8; ++k) {
    float2 af = *(const float2*)(att + d0 + 2 * k);
    at8[k] = {(_Float16)(af.x * L2E), (_Float16)(af.y * L2E)};
  }
  half8v k8 = {(_Float16)0.2f, (_Float16)0.2f, (_Float16)0.2f, (_Float16)0.2f,
               (_Float16)0.2f, (_Float16)0.2f, (_Float16)0.2f, (_Float16)0.2f};
  int e0 = row_ptr[wid];
  int deg = row_ptr[wid + 1] - e0;
  const int* ecol = col + e0;
  float s = 0.f, a[16] = {};
  auto edge = [&](half8v va, half8v vb, bool valid) {
    half8v ua = va + xra;
    half8v ub = vb + xrb;
    half8v la = __builtin_elementwise_max(ua, ua * k8);
    half8v lb = __builtin_elementwise_max(ub, ub * k8);
    float pA = __builtin_amdgcn_fdot2((half2v){la[0], la[1]}, at8[0], 0.f, false);
    pA = __builtin_amdgcn_fdot2((half2v){la[2], la[3]}, at8[1], pA, false);
    pA = __builtin_amdgcn_fdot2((half2v){la[4], la[5]}, at8[2], pA, false);
    pA = __builtin_amdgcn_fdot2((half2v){la[6], la[7]}, at8[3], pA, false);
    float pB = __builtin_amdgcn_fdot2((half2v){lb[0], lb[1]}, at8[4], 0.f, false);
    pB = __builtin_amdgcn_fdot2((half2v){lb[2], lb[3]}, at8[5], pB, false);
    pB = __builtin_amdgcn_fdot2((half2v){lb[4], lb[5]}, at8[6], pB, false);
    pB = __builtin_amdgcn_fdot2((half2v){lb[6], lb[7]}, at8[7], pB, false);
    float p = red4dpp(pA + pB);  // head sum (4 subs)
    float w = valid ? exp2f(p) : 0.f;
    s += w;
#pragma unroll
    for (int k = 0; k < 8; ++k) a[k] = fmaf(w, (float)va[k], a[k]);
#pragma unroll
    for (int k = 0; k < 8; ++k) a[8 + k] = fmaf(w, (float)vb[k], a[8 + k]);
  };
  auto ld = [&](uint node, half8v& va, half8v& vb) {
    const _Float16* p = xl + ((node << 8) | d0);
    va = *(const half8v*)p;
    vb = *(const half8v*)(p + 8);
  };
  {
    half8v sva, svb;
    ld((uint)wid, sva, svb);
    edge(sva, svb, eslot == 0);  // self loop (counted once)
  }
  if (deg > 0) {
    int dm1 = deg - 1;
    half8v vA0, vA1, vB0, vB1, vC0, vC1;
    ld((uint)ecol[min(eslot, dm1)], vA0, vA1);
    ld((uint)ecol[min(eslot + 4, dm1)], vB0, vB1);
    ld((uint)ecol[min(eslot + 8, dm1)], vC0, vC1);
    int M = deg >> 2, pf = eslot + 12;
#pragma unroll 2
    for (int j = 0; j < M; ++j) {
      half8v vD0, vD1;
      ld((uint)ecol[min(pf, dm1)], vD0, vD1);  // prefetch d3
      edge(vA0, vA1, true);
      vA0 = vB0; vA1 = vB1; vB0 = vC0; vB1 = vC1; vC0 = vD0; vC1 = vD1;
      pf += 4;
    }
    int T = deg & 3;
    if (T) edge(vA0, vA1, eslot < T);
  }
  // combine 4 edge slots
  s += __shfl_xor(s, 16); s += __shfl_xor(s, 32);
#pragma unroll
  for (int k = 0; k < 16; ++k) {
    a[k] += __shfl_xor(a[k], 16);
    a[k] += __shfl_xor(a[k], 32);
  }
  float inv = 1.f / (s + 1e-16f);
#pragma unroll
  for (int k = 0; k < 16; ++k) a[k] *= inv;
  // mean over 4 heads: same out-channel lives at subs sub, sub^4, sub^8, sub^12
#pragma unroll
  for (int k = 0; k < 16; ++k) {
    a[k] += __shfl_xor(a[k], 4);
    a[k] += __shfl_xor(a[k], 8);
  }
  if (lane < 4) {
    float* op = out + (size_t)wid * 64 + lane * 16;
#pragma unroll
    for (int q = 0; q < 4; ++q) {
      float4 b = *(const float4*)(bias + lane * 16 + q * 4);
      float4 o = make_float4(a[q * 4 + 0] * 0.25f + b.x, a[q * 4 + 1] * 0.25f + b.y,
                             a[q * 4 + 2] * 0.25f + b.z, a[q * 4 + 3] * 0.25f + b.w);
      *(float4*)(op + q * 4) = o;
    }
  }
}

extern "C" void kernel_launch(void* const* d_in, const int* in_sizes, int n_in,
                              void* d_out, int out_size, void* d_ws, size_t ws_size,
                              hipStream_t stream) {
  const float* x = (const float*)d_in[0];
  const int* ei = (const int*)d_in[1];
  const float* Wl1 = (const float*)d_in[2];
  const float* Wr1 = (const float*)d_in[3];
  const float* att1 = (const float*)d_in[4];
  const float* b1 = (const float*)d_in[5];
  const float* Wl2 = (const float*)d_in[6];
  const float* Wr2 = (const float*)d_in[7];
  const float* att2 = (const float*)d_in[8];
  const float* b2 = (const float*)d_in[9];
  float* out = (float*)d_out;

  int N = in_sizes[0] / 128;
  int E = in_sizes[1] / 2;
  const int* srcArr = ei;
  const int* dstArr = ei + E;

  char* w = (char*)d_ws;
  auto alloc = [&](size_t bytes) {
    char* p = w;
    w += (bytes + 255) & ~(size_t)255;
    return p;
  };
  int* row_ptr = (int*)alloc((size_t)(N + 1) * sizeof(int));
  int* cursor = (int*)alloc((size_t)N * sizeof(int));
  int* partial = (int*)alloc(256 * sizeof(int));
  int* col = (int*)alloc((size_t)E * sizeof(int));
  _Float16* xb = (_Float16*)alloc((size_t)N * 128 * 2);
  _Float16* wb = (_Float16*)alloc(98304 * 2);
  _Float16* hb = (_Float16*)alloc((size_t)N * 128 * 2);
  _Float16* xl1 = (_Float16*)alloc((size_t)N * 128 * 2);
  _Float16* xr1 = (_Float16*)alloc((size_t)N * 128 * 2);
  _Float16* xl2 = (_Float16*)alloc((size_t)N * 256 * 2);
  _Float16* xr2 = (_Float16*)alloc((size_t)N * 256 * 2);

  const _Float16* wl1b = wb;
  const _Float16* wr1b = wb + 16384;
  const _Float16* wl2b = wb + 32768;
  const _Float16* wr2b = wb + 65536;

  // ---- conversions + degree count (fused) ----
  hipMemsetAsync(cursor, 0, (size_t)N * sizeof(int), stream);
  fused_cvt_count_kernel<<<2048, 256, 0, stream>>>(x, Wl1, Wr1, Wl2, Wr2, xb, wb,
                                                   dstArr, cursor, N * 32, E);

  // ---- CSR scan + fill ----
  int nb = (N + 255) / 256;
  partial_kernel<<<nb, 256, 0, stream>>>(cursor, partial, N);
  scan_final_kernel<<<nb, 256, 0, stream>>>(cursor, partial, row_ptr, cursor, N, E, nb);
  fill_kernel<<<(E + 255) / 256, 256, 0, stream>>>(srcArr, dstArr, cursor, col, E);

  int gx = (N + 63) / 64;
  int aggBlocks = (N * 64 + 127) / 128;
  // ---- layer 1 ----
  gemm_mfma2<<<dim3(gx, 1), 256, 0, stream>>>(xb, wl1b, wr1b, xl1, xr1, N, 128, 128);
  agg1_kernel<<<aggBlocks, 128, 0, stream>>>(xl1, xr1, att1, b1, row_ptr, col, hb, N);

  // ---- layer 2 ----
  gemm_mfma2<<<dim3(gx, 2), 256, 0, stream>>>(hb, wl2b, wr2b, xl2, xr2, N, 256, 256);
  agg2_kernel<<<aggBlocks, 128, 0, stream>>>(xl2, xr2, att2, b2, row_ptr, col, out, N);
}

// Round 11
// 186.552 us; speedup vs baseline: 1.0529x; 1.0529x over previous
//
#include <hip/hip_runtime.h>
#include <hip/hip_bf16.h>
#include <math.h>

// ---------------------------------------------------------------------------
// GATv2 2-layer forward. N=50000, E=500000 (+N self loops), IN_F=128, H=4.
// Round 11: agg2 reverted to round-8 (2-edge, f16 pk accum; round-10 4-edge
// cost 18pt occupancy and +12us). agg1 stays 4-edge (round-10 win). gemm1
// reads f32 x directly (kills x-conversion pass). CSR/scan unchanged.
// ---------------------------------------------------------------------------

typedef _Float16 half2v __attribute__((ext_vector_type(2)));
typedef _Float16 half4v __attribute__((ext_vector_type(4)));
typedef _Float16 half8v __attribute__((ext_vector_type(8)));
typedef float float4v __attribute__((ext_vector_type(4)));

template <int CTRL>
static __device__ __forceinline__ float dppadd(float x) {
  int y = __builtin_amdgcn_update_dpp(0, __float_as_int(x), CTRL, 0xf, 0xf, true);
  return x + __int_as_float(y);
}

// sum across each aligned 4-lane quad
static __device__ __forceinline__ float red4dpp(float p) {
  p = dppadd<0xB1>(p);  // quad_perm xor1
  p = dppadd<0x4E>(p);  // quad_perm xor2
  return p;
}

// sum across each 8-lane group
static __device__ __forceinline__ float red8dpp(float p) {
  p = dppadd<0xB1>(p);   // quad_perm xor1
  p = dppadd<0x4E>(p);   // quad_perm xor2
  p = dppadd<0x141>(p);  // row_half_mirror: other quad within 8
  return p;
}

// ---------------- weight conversion + degree count ----------------

__global__ void cvt_w_count_kernel(
    const float* __restrict__ wl1, const float* __restrict__ wr1,
    const float* __restrict__ wl2, const float* __restrict__ wr2,
    _Float16* __restrict__ wb,
    const int* __restrict__ dst, int* __restrict__ deg, int E) {
  int i = blockIdx.x * blockDim.x + threadIdx.x;
  int stride = gridDim.x * blockDim.x;
  int total = 24576 + E;
  for (; i < total; i += stride) {
    if (i < 24576) {
      int fj = i * 4;
      const float* src;
      int so;
      if (fj < 16384) { src = wl1; so = fj; }
      else if (fj < 32768) { src = wr1; so = fj - 16384; }
      else if (fj < 65536) { src = wl2; so = fj - 32768; }
      else { src = wr2; so = fj - 65536; }
      float4 v = *(const float4*)(src + so);
      half4v o = {(_Float16)v.x, (_Float16)v.y, (_Float16)v.z, (_Float16)v.w};
      *(half4v*)(wb + fj) = o;
    } else {
      atomicAdd(&deg[dst[i - 24576]], 1);
    }
  }
}

// ---------------- CSR build ----------------

__global__ void partial_kernel(const int* __restrict__ deg, int* __restrict__ partial, int N) {
  int t = threadIdx.x;
  int i = blockIdx.x * 256 + t;
  int v = (i < N) ? deg[i] : 0;
  v += __shfl_xor(v, 1); v += __shfl_xor(v, 2); v += __shfl_xor(v, 4);
  v += __shfl_xor(v, 8); v += __shfl_xor(v, 16); v += __shfl_xor(v, 32);
  __shared__ int ws[4];
  if ((t & 63) == 0) ws[t >> 6] = v;
  __syncthreads();
  if (t == 0) partial[blockIdx.x] = ws[0] + ws[1] + ws[2] + ws[3];
}

__global__ void scan_final_kernel(const int* __restrict__ deg, const int* __restrict__ partial,
                                  int* __restrict__ row_ptr, int* __restrict__ cursor,
                                  int N, int E, int nb) {
  __shared__ int sp[256];
  __shared__ int s[256];
  int t = threadIdx.x;
  int pv = (t < nb) ? partial[t] : 0;
  sp[t] = pv;
  __syncthreads();
  for (int off = 1; off < 256; off <<= 1) {
    int u = (t >= off) ? sp[t - off] : 0;
    __syncthreads();
    sp[t] += u;
    __syncthreads();
  }
  int blockpre = (blockIdx.x > 0) ? sp[blockIdx.x - 1] : 0;
  int i = blockIdx.x * 256 + t;
  int v = (i < N) ? deg[i] : 0;
  s[t] = v;
  __syncthreads();
  for (int off = 1; off < 256; off <<= 1) {
    int u = (t >= off) ? s[t - off] : 0;
    __syncthreads();
    s[t] += u;
    __syncthreads();
  }
  int excl = s[t] - v + blockpre;
  if (i < N) {
    row_ptr[i] = excl;
    cursor[i] = excl;
  }
  if (blockIdx.x == 0 && t == 0) row_ptr[N] = E;
}

__global__ void fill_kernel(const int* __restrict__ src, const int* __restrict__ dst,
                            int* __restrict__ cursor, int* __restrict__ col, int E) {
  int i = blockIdx.x * blockDim.x + threadIdx.x;
  if (i < E) {
    int d = dst[i];
    int pos = atomicAdd(&cursor[d], 1);
    col[pos] = src[i];
  }
}

// ---------------- fp16 MFMA GEMM, LDS-staged W ----------------
// AF32: A is f32 (layer 1 reads x directly, converts to f16 fragments).
template <bool AF32>
__global__ __launch_bounds__(256) void gemm_mfma2(
    const void* __restrict__ Av, const _Float16* __restrict__ Wa,
    const _Float16* __restrict__ Wb, _Float16* __restrict__ Ca,
    _Float16* __restrict__ Cb, int N, int Oa, int ldC) {
  __shared__ _Float16 lds[32768];  // 64KB
  int t = threadIdx.x;
  int gbase = blockIdx.y * 256;
#pragma unroll
  for (int i = 0; i < 16; ++i) {
    int c = t + i * 256;
    int row = c >> 4, kc = c & 15;
    int grow = gbase + row;
    const _Float16* srcW =
        (grow < Oa) ? (Wa + (size_t)grow * 128) : (Wb + (size_t)(grow - Oa) * 128);
    half8v v = *(const half8v*)(srcW + kc * 8);
    int off16 = (row << 4) | (kc ^ (row & 7));
    *(half8v*)((char*)lds + (off16 << 4)) = v;
  }
  __syncthreads();
  int wv = t >> 6, lane = t & 63;
  int l15 = lane & 15, l4 = lane >> 4;
  int row0 = blockIdx.x * 64 + (wv & 1) * 32;
  int colw = (wv >> 1) * 128;
  int gc = gbase + colw;
  half8v xf[2][4];
#pragma unroll
  for (int rg = 0; rg < 2; ++rg) {
    int r = row0 + rg * 16 + l15;
    bool valid = r < N;
    if constexpr (AF32) {
      const float* Ar = (const float*)Av + (size_t)r * 128 + l4 * 8;
#pragma unroll
      for (int kk = 0; kk < 4; ++kk) {
        half8v z = {};
        if (valid) {
          float4 q0 = *(const float4*)(Ar + kk * 32);
          float4 q1 = *(const float4*)(Ar + kk * 32 + 4);
          z = half8v{(_Float16)q0.x, (_Float16)q0.y, (_Float16)q0.z, (_Float16)q0.w,
                     (_Float16)q1.x, (_Float16)q1.y, (_Float16)q1.z, (_Float16)q1.w};
        }
        xf[rg][kk] = z;
      }
    } else {
      const half8v* Ar = (const half8v*)((const _Float16*)Av + (size_t)r * 128 + l4 * 8);
#pragma unroll
      for (int kk = 0; kk < 4; ++kk) {
        half8v z = {};
        xf[rg][kk] = valid ? Ar[kk * 4] : z;
      }
    }
  }
  int wrow = colw + l15;
  float4v acc[2][8] = {};
#pragma unroll
  for (int kk = 0; kk < 4; ++kk) {
    int xorterm = ((kk * 4 + l4) ^ (l15 & 7)) << 4;
    const char* base = (const char*)lds + wrow * 256 + xorterm;
    half8v wf[8];
#pragma unroll
    for (int ot = 0; ot < 8; ++ot) wf[ot] = *(const half8v*)(base + ot * 4096);
#pragma unroll
    for (int ot = 0; ot < 8; ++ot) {
      acc[0][ot] = __builtin_amdgcn_mfma_f32_16x16x32_f16(wf[ot], xf[0][kk], acc[0][ot], 0, 0, 0);
      acc[1][ot] = __builtin_amdgcn_mfma_f32_16x16x32_f16(wf[ot], xf[1][kk], acc[1][ot], 0, 0, 0);
    }
  }
  bool isA = gc < Oa;
  _Float16* C = isA ? Ca : Cb;
  int cb = isA ? gc : gc - Oa;
#pragma unroll
  for (int rg = 0; rg < 2; ++rg) {
    int r = row0 + rg * 16 + l15;
    if (r < N) {
#pragma unroll
      for (int ot = 0; ot < 8; ++ot) {
        half4v o = {(_Float16)acc[rg][ot][0], (_Float16)acc[rg][ot][1],
                    (_Float16)acc[rg][ot][2], (_Float16)acc[rg][ot][3]};
        *(half4v*)(C + (size_t)r * ldC + cb + ot * 16 + l4 * 4) = o;
      }
    }
  }
}

// ---------------- aggregation ----------------
// No max-subtraction (logits O(6), softmax shift-invariant). att pre-scaled
// by log2(e) so w = exp2(p).

// Layer 1 (round-10 structure): 4 edges/wave, 16 lanes/edge, 8 ch/lane.
__global__ __launch_bounds__(128) void agg1_kernel(
    const _Float16* __restrict__ xl, const _Float16* __restrict__ xr,
    const float* __restrict__ att, const float* __restrict__ bias,
    const int* __restrict__ row_ptr, const int* __restrict__ col,
    _Float16* __restrict__ hout, int N) {
  int wid = (blockIdx.x * blockDim.x + threadIdx.x) >> 6;
  int lane = threadIdx.x & 63;
  if (wid >= N) return;
  int eslot = lane >> 4, sub = lane & 15;
  const uint d0 = (uint)sub * 8u;
  const float L2E = 1.44269504f;
  half8v xrv = *(const half8v*)(xr + (((uint)wid << 7) | d0));
  float4 af0 = *(const float4*)(att + d0);
  float4 af1 = *(const float4*)(att + d0 + 4);
  half2v at4[4] = {{(_Float16)(af0.x * L2E), (_Float16)(af0.y * L2E)},
                   {(_Float16)(af0.z * L2E), (_Float16)(af0.w * L2E)},
                   {(_Float16)(af1.x * L2E), (_Float16)(af1.y * L2E)},
                   {(_Float16)(af1.z * L2E), (_Float16)(af1.w * L2E)}};
  half8v k8 = {(_Float16)0.2f, (_Float16)0.2f, (_Float16)0.2f, (_Float16)0.2f,
               (_Float16)0.2f, (_Float16)0.2f, (_Float16)0.2f, (_Float16)0.2f};
  int e0 = row_ptr[wid];
  int deg = row_ptr[wid + 1] - e0;
  const int* ecol = col + e0;
  float s = 0.f, a[8] = {};
  auto edge = [&](half8v v, bool valid) {
    half8v u = v + xrv;
    half8v lr = __builtin_elementwise_max(u, u * k8);
    float pA = __builtin_amdgcn_fdot2((half2v){lr[0], lr[1]}, at4[0], 0.f, false);
    pA = __builtin_amdgcn_fdot2((half2v){lr[2], lr[3]}, at4[1], pA, false);
    float pB = __builtin_amdgcn_fdot2((half2v){lr[4], lr[5]}, at4[2], 0.f, false);
    pB = __builtin_amdgcn_fdot2((half2v){lr[6], lr[7]}, at4[3], pB, false);
    float p = red4dpp(pA + pB);  // head sum (4 subs)
    float w = valid ? exp2f(p) : 0.f;
    s += w;
#pragma unroll
    for (int k = 0; k < 8; ++k) a[k] = fmaf(w, (float)v[k], a[k]);
  };
  auto ld = [&](uint node) { return *(const half8v*)(xl + ((node << 7) | d0)); };
  edge(ld((uint)wid), eslot == 0);  // self loop (counted once)
  if (deg > 0) {
    int dm1 = deg - 1;
    half8v vA = ld((uint)ecol[min(eslot, dm1)]);
    half8v vB = ld((uint)ecol[min(eslot + 4, dm1)]);
    half8v vC = ld((uint)ecol[min(eslot + 8, dm1)]);
    int M = deg >> 2, pf = eslot + 12;
#pragma unroll 2
    for (int j = 0; j < M; ++j) {
      half8v vD = ld((uint)ecol[min(pf, dm1)]);  // prefetch d3
      edge(vA, true);
      vA = vB; vB = vC; vC = vD; pf += 4;
    }
    int T = deg & 3;
    if (T) edge(vA, eslot < T);
  }
  s += __shfl_xor(s, 16); s += __shfl_xor(s, 32);
#pragma unroll
  for (int k = 0; k < 8; ++k) {
    a[k] += __shfl_xor(a[k], 16);
    a[k] += __shfl_xor(a[k], 32);
  }
  float inv = 1.f / (s + 1e-16f);
  if (eslot == 0) {
    float4 b0 = *(const float4*)(bias + d0);
    float4 b1 = *(const float4*)(bias + d0 + 4);
    float bb[8] = {b0.x, b0.y, b0.z, b0.w, b1.x, b1.y, b1.z, b1.w};
    half8v o;
#pragma unroll
    for (int k = 0; k < 8; ++k) {
      float tv = a[k] * inv + bb[k];
      tv = tv > 0.f ? tv : __expf(tv) - 1.f;  // ELU
      o[k] = (_Float16)tv;
    }
    *(half8v*)(hout + (((uint)wid << 7) | d0)) = o;
  }
}

// Layer 2 (round-8 structure): 2 edges/wave, 8 ch/lane, f16 packed accum
// with logit shift 10 (cancels in alpha), s in f32.
__global__ __launch_bounds__(128) void agg2_kernel(
    const _Float16* __restrict__ xl, const _Float16* __restrict__ xr,
    const float* __restrict__ att, const float* __restrict__ bias,
    const int* __restrict__ row_ptr, const int* __restrict__ col,
    float* __restrict__ out, int N) {
  int wid = (blockIdx.x * blockDim.x + threadIdx.x) >> 6;
  int lane = threadIdx.x & 63;
  if (wid >= N) return;
  int eslot = lane >> 5, sub = lane & 31;
  const uint d0 = (uint)sub * 8u;
  const float L2E = 1.44269504f;
  const float SH = 10.f;
  half8v xrv = *(const half8v*)(xr + (((uint)wid << 8) | d0));
  float4 af0 = *(const float4*)(att + d0);
  float4 af1 = *(const float4*)(att + d0 + 4);
  half2v at[4] = {{(_Float16)(af0.x * L2E), (_Float16)(af0.y * L2E)},
                  {(_Float16)(af0.z * L2E), (_Float16)(af0.w * L2E)},
                  {(_Float16)(af1.x * L2E), (_Float16)(af1.y * L2E)},
                  {(_Float16)(af1.z * L2E), (_Float16)(af1.w * L2E)}};
  half8v k8 = {(_Float16)0.2f, (_Float16)0.2f, (_Float16)0.2f, (_Float16)0.2f,
               (_Float16)0.2f, (_Float16)0.2f, (_Float16)0.2f, (_Float16)0.2f};
  int e0 = row_ptr[wid];
  int deg = row_ptr[wid + 1] - e0;
  const int* ecol = col + e0;
  float s;
  half8v ach;
  {  // self loop
    half8v v = *(const half8v*)(xl + (((uint)wid << 8) | d0));
    half8v u = v + xrv;
    half8v lr = __builtin_elementwise_max(u, u * k8);
    float p = __builtin_amdgcn_fdot2((half2v){lr[0], lr[1]}, at[0], 0.f, false);
    p = __builtin_amdgcn_fdot2((half2v){lr[2], lr[3]}, at[1], p, false);
    p = __builtin_amdgcn_fdot2((half2v){lr[4], lr[5]}, at[2], p, false);
    p = __builtin_amdgcn_fdot2((half2v){lr[6], lr[7]}, at[3], p, false);
    p = red8dpp(p);
    float w = (eslot == 0) ? exp2f(p - SH) : 0.f;
    s = w;
    _Float16 wh = (_Float16)w;
    half8v w8 = {wh, wh, wh, wh, wh, wh, wh, wh};
    ach = v * w8;
  }
  if (deg > 0) {
    int dm1 = deg - 1;
    int cA = ecol[min(eslot, dm1)];
    int cB = ecol[min(eslot + 2, dm1)];
    int cC = ecol[min(eslot + 4, dm1)];
    half8v vA = *(const half8v*)(xl + (((uint)cA << 8) | d0));
    half8v vB = *(const half8v*)(xl + (((uint)cB << 8) | d0));
    half8v vC = *(const half8v*)(xl + (((uint)cC << 8) | d0));
    int M = deg >> 1;
    int pf = eslot + 6;
#pragma unroll 3
    for (int j = 0; j < M; ++j) {
      int cD = ecol[min(pf, dm1)];
      half8v vD = *(const half8v*)(xl + (((uint)cD << 8) | d0));  // prefetch d3
      half8v u = vA + xrv;
      half8v lr = __builtin_elementwise_max(u, u * k8);
      float p = __builtin_amdgcn_fdot2((half2v){lr[0], lr[1]}, at[0], 0.f, false);
      p = __builtin_amdgcn_fdot2((half2v){lr[2], lr[3]}, at[1], p, false);
      p = __builtin_amdgcn_fdot2((half2v){lr[4], lr[5]}, at[2], p, false);
      p = __builtin_amdgcn_fdot2((half2v){lr[6], lr[7]}, at[3], p, false);
      p = red8dpp(p);
      float w = exp2f(p - SH);
      s += w;
      _Float16 wh = (_Float16)w;
      half8v w8 = {wh, wh, wh, wh, wh, wh, wh, wh};
      ach += vA * w8;  // 4x v_pk_fma_f16
      vA = vB; vB = vC; vC = vD; pf += 2;
    }
    if (deg & 1) {
      half8v u = vA + xrv;
      half8v lr = __builtin_elementwise_max(u, u * k8);
      float p = __builtin_amdgcn_fdot2((half2v){lr[0], lr[1]}, at[0], 0.f, false);
      p = __builtin_amdgcn_fdot2((half2v){lr[2], lr[3]}, at[1], p, false);
      p = __builtin_amdgcn_fdot2((half2v){lr[4], lr[5]}, at[2], p, false);
      p = __builtin_amdgcn_fdot2((half2v){lr[6], lr[7]}, at[3], p, false);
      p = red8dpp(p);
      float w = (eslot == 0) ? exp2f(p - SH) : 0.f;
      s += w;
      _Float16 wh = (_Float16)w;
      half8v w8 = {wh, wh, wh, wh, wh, wh, wh, wh};
      ach += vA * w8;
    }
  }
  // combine edge slots
  s += __shfl_xor(s, 32);
  float ac[8];
#pragma unroll
  for (int k = 0; k < 8; ++k) {
    ac[k] = (float)ach[k];
    ac[k] += __shfl_xor(ac[k], 32);
  }
  float inv = 1.f / (s + 1e-16f);
#pragma unroll
  for (int k = 0; k < 8; ++k) ac[k] *= inv;
  // mean over 4 heads: heads live at sub, sub^8, sub^16, sub^24
#pragma unroll
  for (int k = 0; k < 8; ++k) {
    ac[k] += __shfl_xor(ac[k], 8);
    ac[k] += __shfl_xor(ac[k], 16);
  }
  if (lane < 8) {
    float4 b0 = *(const float4*)(bias + lane * 8);
    float4 b1v = *(const float4*)(bias + lane * 8 + 4);
    float4 o0 = make_float4(ac[0] * 0.25f + b0.x, ac[1] * 0.25f + b0.y,
                            ac[2] * 0.25f + b0.z, ac[3] * 0.25f + b0.w);
    float4 o1 = make_float4(ac[4] * 0.25f + b1v.x, ac[5] * 0.25f + b1v.y,
                            ac[6] * 0.25f + b1v.z, ac[7] * 0.25f + b1v.w);
    float* op = out + (size_t)wid * 64 + lane * 8;
    *(float4*)op = o0;
    *(float4*)(op + 4) = o1;
  }
}

extern "C" void kernel_launch(void* const* d_in, const int* in_sizes, int n_in,
                              void* d_out, int out_size, void* d_ws, size_t ws_size,
                              hipStream_t stream) {
  const float* x = (const float*)d_in[0];
  const int* ei = (const int*)d_in[1];
  const float* Wl1 = (const float*)d_in[2];
  const float* Wr1 = (const float*)d_in[3];
  const float* att1 = (const float*)d_in[4];
  const float* b1 = (const float*)d_in[5];
  const float* Wl2 = (const float*)d_in[6];
  const float* Wr2 = (const float*)d_in[7];
  const float* att2 = (const float*)d_in[8];
  const float* b2 = (const float*)d_in[9];
  float* out = (float*)d_out;

  int N = in_sizes[0] / 128;
  int E = in_sizes[1] / 2;
  const int* srcArr = ei;
  const int* dstArr = ei + E;

  char* w = (char*)d_ws;
  auto alloc = [&](size_t bytes) {
    char* p = w;
    w += (bytes + 255) & ~(size_t)255;
    return p;
  };
  int* row_ptr = (int*)alloc((size_t)(N + 1) * sizeof(int));
  int* cursor = (int*)alloc((size_t)N * sizeof(int));
  int* partial = (int*)alloc(256 * sizeof(int));
  int* col = (int*)alloc((size_t)E * sizeof(int));
  _Float16* wb = (_Float16*)alloc(98304 * 2);
  _Float16* hb = (_Float16*)alloc((size_t)N * 128 * 2);
  _Float16* xl1 = (_Float16*)alloc((size_t)N * 128 * 2);
  _Float16* xr1 = (_Float16*)alloc((size_t)N * 128 * 2);
  _Float16* xl2 = (_Float16*)alloc((size_t)N * 256 * 2);
  _Float16* xr2 = (_Float16*)alloc((size_t)N * 256 * 2);

  const _Float16* wl1b = wb;
  const _Float16* wr1b = wb + 16384;
  const _Float16* wl2b = wb + 32768;
  const _Float16* wr2b = wb + 65536;

  // ---- weight conversion + degree count ----
  hipMemsetAsync(cursor, 0, (size_t)N * sizeof(int), stream);
  cvt_w_count_kernel<<<1024, 256, 0, stream>>>(Wl1, Wr1, Wl2, Wr2, wb, dstArr, cursor, E);

  // ---- CSR scan + fill ----
  int nb = (N + 255) / 256;
  partial_kernel<<<nb, 256, 0, stream>>>(cursor, partial, N);
  scan_final_kernel<<<nb, 256, 0, stream>>>(cursor, partial, row_ptr, cursor, N, E, nb);
  fill_kernel<<<(E + 255) / 256, 256, 0, stream>>>(srcArr, dstArr, cursor, col, E);

  int gx = (N + 63) / 64;
  int aggBlocks = (N * 64 + 127) / 128;
  // ---- layer 1 (A = f32 x, converted in-kernel) ----
  gemm_mfma2<true><<<dim3(gx, 1), 256, 0, stream>>>(x, wl1b, wr1b, xl1, xr1, N, 128, 128);
  agg1_kernel<<<aggBlocks, 128, 0, stream>>>(xl1, xr1, att1, b1, row_ptr, col, hb, N);

  // ---- layer 2 ----
  gemm_mfma2<false><<<dim3(gx, 2), 256, 0, stream>>>(hb, wl2b, wr2b, xl2, xr2, N, 256, 256);
  agg2_kernel<<<aggBlocks, 128, 0, stream>>>(xl2, xr2, att2, b2, row_ptr, col, out, N);
}